// Round 10
// baseline (159.682 us; speedup 1.0000x reference)
//
#include <hip/hip_runtime.h>

// RandomAffine, pipelined tile processing.
// Each 256-thread block handles NT=4 consecutive j-tiles (32x32 output each).
// While computing tile t from LDS, the block issues tile t+1's bbox loads
// into registers (8 float4/thread, fixed 48x39-float4 fill shape); after the
// barrier they are written to the single 30KB LDS buffer. This overlaps HBM
// reads with compute while keeping the whole 1024-block grid resident
// (4 blocks/CU). Border tiles (x-range crossing the image edge) use a scalar
// reflect fill path after the barrier.

#define IMG_H 2048
#define IMG_W 2048
#define TILE  32
#define NT    4            // j-tiles per block
#define BBH   48           // staged rows  (worst span 44 + 4 margin)
#define NV4   39           // staged float4 slots per row (52 px * 3 / 4)
#define BBW3  (NV4 * 4)    // 156 floats per staged row
#define NELEM (BBH * NV4)  // 1872 float4 per tile fill
#define PF    8            // prefetch float4 per thread (8*256=2048 >= 1872)

__device__ __forceinline__ int reflect2048(int i) {
    // scipy 'reflect' (duplicate-edge), period 2n, n=2048.
    int p = i & 4095;
    return (p < 2048) ? p : (4095 - p);
}

__global__ __launch_bounds__(256) void affine_pipe_kernel(
    const float* __restrict__ img, const float* __restrict__ Mp,
    float* __restrict__ out)
{
    __shared__ float lds[BBH * BBW3];      // 29952 B

    const int tid = threadIdx.x;
    const int grp = blockIdx.x & 15;       // 16 groups of NT tiles along j
    const int tby = blockIdx.x >> 4;       // 64 tile-rows
    const int i0 = tby * TILE;
    const int j0base = grp * (TILE * NT);

    const float step = 2048.0f / 2047.0f;
    const float m00 = Mp[0], m01 = Mp[1];
    const float m10 = Mp[3], m11 = Mp[4];
    const float b0 = Mp[6] + 1024.0f, b1 = Mp[7] + 1024.0f;

    const float yv0 = fmaf((float)i0,            step, -1024.0f);
    const float yv1 = fmaf((float)(i0 + TILE-1), step, -1024.0f);

    // Per-tile bbox from the 4 corners (affine -> extremes at corners).
    auto bbox = [&](int j0, int& y0, int& x0, bool& fast) {
        const float xva = fmaf((float)j0,          step, -1024.0f);
        const float xvb = fmaf((float)(j0+TILE-1), step, -1024.0f);
        const float rya = yv0*m00 + xva*m10 + b0, ryb = yv0*m00 + xvb*m10 + b0;
        const float ryc = yv1*m00 + xva*m10 + b0, ryd = yv1*m00 + xvb*m10 + b0;
        const float rxa = yv0*m01 + xva*m11 + b1, rxb = yv0*m01 + xvb*m11 + b1;
        const float rxc = yv1*m01 + xva*m11 + b1, rxd = yv1*m01 + xvb*m11 + b1;
        y0 = (int)floorf(fminf(fminf(rya,ryb), fminf(ryc,ryd))) - 1;
        x0 = ((int)floorf(fminf(fminf(rxa,rxb), fminf(rxc,rxd))) - 1) & ~3;
        fast = (x0 >= 0) && (x0*3 + NV4*4 <= IMG_W*3);   // x0 <= 1996
    };

    float4 pf[PF];

    auto issue = [&](int y0, int x0) {       // global -> regs (fire & forget)
        #pragma unroll
        for (int k = 0; k < PF; ++k) {
            const int e = tid + 256*k;
            if (e < NELEM) {
                const int r = e / NV4, s = e - r*NV4;   // const-divisor magic
                const int gy = reflect2048(y0 + r);
                pf[k] = *(const float4*)(img + gy*(IMG_W*3) + x0*3 + s*4);
            }
        }
    };
    auto writeback = [&]() {                 // regs -> LDS (waits vmcnt)
        #pragma unroll
        for (int k = 0; k < PF; ++k) {
            const int e = tid + 256*k;
            if (e < NELEM) {
                const int r = e / NV4, s = e - r*NV4;
                *(float4*)&lds[r*BBW3 + s*4] = pf[k];
            }
        }
    };
    auto slowfill = [&](int y0, int x0) {    // border tiles: scalar reflect
        for (int e = tid; e < BBH*52; e += 256) {
            const int r  = e / 52;
            const int xx = e - r*52;
            const int gy = reflect2048(y0 + r);
            const int gx = reflect2048(x0 + xx);
            const float* s = img + (gy*IMG_W + gx)*3;
            float* d = &lds[r*BBW3 + xx*3];
            d[0] = s[0]; d[1] = s[1]; d[2] = s[2];
        }
    };

    auto compute = [&](int j0, int y0, int x0) {
        const int row = tid >> 3;            // 32 rows
        const int col = (tid & 7) * 4;       // 4 consecutive px per thread
        const int i = i0 + row;
        const float yv = fmaf((float)i, step, -1024.0f);
        float v[12];
        #pragma unroll
        for (int k = 0; k < 4; ++k) {
            const float xv = fmaf((float)(j0 + col + k), step, -1024.0f);
            const float ry = yv*m00 + xv*m10 + b0;
            const float rx = yv*m01 + xv*m11 + b1;
            const float fy = floorf(ry), fx = floorf(rx);
            const float wy1 = ry - fy, wx1 = rx - fx;
            const float wy0 = 1.0f - wy1, wx0 = 1.0f - wx1;
            const int iy = (int)fy - y0;
            const int ix = (int)fx - x0;
            const float* p0 = &lds[iy*BBW3 + ix*3];
            const float* p1 = p0 + BBW3;
            const float w00 = wy0*wx0, w01 = wy0*wx1;
            const float w10 = wy1*wx0, w11 = wy1*wx1;
            v[k*3+0] = w00*p0[0] + w01*p0[3] + w10*p1[0] + w11*p1[3];
            v[k*3+1] = w00*p0[1] + w01*p0[4] + w10*p1[1] + w11*p1[4];
            v[k*3+2] = w00*p0[2] + w01*p0[5] + w10*p1[2] + w11*p1[5];
        }
        float* ob = out + (i*IMG_W + j0 + col)*3;   // 48B chunk, 16B aligned
        *(float4*)(ob+0) = make_float4(v[0], v[1], v[2],  v[3]);
        *(float4*)(ob+4) = make_float4(v[4], v[5], v[6],  v[7]);
        *(float4*)(ob+8) = make_float4(v[8], v[9], v[10], v[11]);
    };

    // ---- Pipeline over NT tiles.
    int y0c, x0c; bool fastc;
    bbox(j0base, y0c, x0c, fastc);
    if (fastc) { issue(y0c, x0c); writeback(); }
    else       { slowfill(y0c, x0c); }
    __syncthreads();

    for (int t = 0; t < NT; ++t) {
        const int j0 = j0base + t*TILE;
        int y0n, x0n; bool fastn = false;
        const bool havenext = (t+1 < NT);
        if (havenext) {
            bbox(j0 + TILE, y0n, x0n, fastn);
            if (fastn) issue(y0n, x0n);      // loads in flight under compute
        }
        compute(j0, y0c, x0c);
        __syncthreads();                     // everyone done reading lds
        if (havenext) {
            if (fastn) writeback();
            else       slowfill(y0n, x0n);
            y0c = y0n; x0c = x0n;
            __syncthreads();                 // lds refilled for next tile
        }
    }
}

extern "C" void kernel_launch(void* const* d_in, const int* in_sizes, int n_in,
                              void* d_out, int out_size, void* d_ws, size_t ws_size,
                              hipStream_t stream) {
    const float* img = (const float*)d_in[0];   // (2048,2048,3) f32
    const float* M   = (const float*)d_in[1];   // (3,3) f32 row-major
    float* out = (float*)d_out;                 // (2048,2048,3) f32

    dim3 grid((IMG_H / TILE) * (IMG_W / (TILE * NT))), block(256);
    hipLaunchKernelGGL(affine_pipe_kernel, grid, block, 0, stream, img, M, out);
}

// Round 11
// 121.901 us; speedup vs baseline: 1.3099x; 1.3099x over previous
//
#include <hip/hip_runtime.h>

// RandomAffine: double-buffered LDS pipeline with global_load_lds DMA.
// Each 256-thread block handles NT=8 consecutive j-tiles (32x32 output).
// Per tile: issue next tile's bbox DMA into buf^1, compute current tile from
// buf, one __syncthreads() (its vmcnt(0) drain completes the prefetch, now
// overlapped with compute instead of naked). 512 blocks = 2 resident
// blocks/CU (LDS-bound), whole grid resident. No register staging -> no
// scratch spills (R10 lesson: WRITE_SIZE 164MB was pf[] spill traffic).

#define IMG_H 2048
#define IMG_W 2048
#define TILE  32
#define NT    8            // j-tiles per block
#define BBH   48           // staged rows capacity (worst dynamic span <= 48)
#define NV4   39           // float4 slots per staged row (52 px * 3 / 4)
#define BBW3  (NV4 * 4)    // 156 floats per staged row
#define BUFN  (BBH * BBW3) // 7488 floats = 29952 B per buffer

__device__ __forceinline__ int reflect2048(int i) {
    // scipy 'reflect' (duplicate-edge), period 2n, n=2048.
    int p = i & 4095;
    return (p < 2048) ? p : (4095 - p);
}

__device__ __forceinline__ void gl2lds16(const float* g, float* l) {
    // 16B per lane, LDS dest = wave-uniform base + lane*16 (HW rule).
    __builtin_amdgcn_global_load_lds(
        (const __attribute__((address_space(1))) void*)g,
        (__attribute__((address_space(3))) void*)l,
        16, 0, 0);
}

__global__ __launch_bounds__(256) void affine_dbuf_kernel(
    const float* __restrict__ img, const float* __restrict__ Mp,
    float* __restrict__ out)
{
    __shared__ float lds[2][BUFN];       // 59904 B total

    const int tid = threadIdx.x;
    const int grp = blockIdx.x & 7;      // 8 groups of NT tiles along j
    const int tby = blockIdx.x >> 3;     // 64 tile-rows
    const int i0 = tby * TILE;
    const int j0base = grp * (TILE * NT);

    const float step = 2048.0f / 2047.0f;
    const float m00 = Mp[0], m01 = Mp[1];
    const float m10 = Mp[3], m11 = Mp[4];
    const float b0 = Mp[6] + 1024.0f, b1 = Mp[7] + 1024.0f;

    const float yv0 = fmaf((float)i0,            step, -1024.0f);
    const float yv1 = fmaf((float)(i0 + TILE-1), step, -1024.0f);

    // Per-tile bbox from the 4 corners (affine -> extremes at corners).
    auto bbox = [&](int j0, int& y0, int& x0, int& nrows, int& nv4, bool& fast) {
        const float xva = fmaf((float)j0,          step, -1024.0f);
        const float xvb = fmaf((float)(j0+TILE-1), step, -1024.0f);
        const float rya = yv0*m00 + xva*m10 + b0, ryb = yv0*m00 + xvb*m10 + b0;
        const float ryc = yv1*m00 + xva*m10 + b0, ryd = yv1*m00 + xvb*m10 + b0;
        const float rxa = yv0*m01 + xva*m11 + b1, rxb = yv0*m01 + xvb*m11 + b1;
        const float rxc = yv1*m01 + xva*m11 + b1, rxd = yv1*m01 + xvb*m11 + b1;
        const float miny = fminf(fminf(rya,ryb), fminf(ryc,ryd));
        const float maxy = fmaxf(fmaxf(rya,ryb), fmaxf(ryc,ryd));
        const float minx = fminf(fminf(rxa,rxb), fminf(rxc,rxd));
        const float maxx = fmaxf(fmaxf(rxa,rxb), fmaxf(rxc,rxd));
        y0 = (int)floorf(miny) - 1;
        nrows = (int)floorf(maxy) + 3 - y0;              // <= 48
        x0 = ((int)floorf(minx) - 1) & ~3;               // 16B align
        const int xw = (int)floorf(maxx) + 3 - x0;       // <= 51
        nv4 = (xw * 3 + 3) >> 2;                         // <= 39
        fast = (x0 >= 0) && (x0*3 + nv4*4 <= IMG_W*3);
    };

    auto dmafill = [&](float* buf, int y0, int x0, int nrows, int nv4) {
        const int wid = tid >> 6, lane = tid & 63;
        if (lane < nv4) {
            for (int r = wid; r < nrows; r += 4) {
                const int gy = reflect2048(y0 + r);
                gl2lds16(img + gy*(IMG_W*3) + x0*3 + lane*4, &buf[r*BBW3]);
            }
        }
    };
    auto slowfill = [&](float* buf, int y0, int x0, int nrows) {
        for (int e = tid; e < nrows*52; e += 256) {
            const int r  = e / 52;
            const int xx = e - r*52;
            const int gy = reflect2048(y0 + r);
            const int gx = reflect2048(x0 + xx);
            const float* s = img + (gy*IMG_W + gx)*3;
            float* d = &buf[r*BBW3 + xx*3];
            d[0] = s[0]; d[1] = s[1]; d[2] = s[2];
        }
    };

    auto compute = [&](const float* buf, int j0, int y0, int x0) {
        const int row = tid >> 3;            // 32 rows
        const int col = (tid & 7) * 4;       // 4 consecutive px per thread
        const int i = i0 + row;
        const float yv = fmaf((float)i, step, -1024.0f);
        float v[12];
        #pragma unroll
        for (int k = 0; k < 4; ++k) {
            const float xv = fmaf((float)(j0 + col + k), step, -1024.0f);
            const float ry = yv*m00 + xv*m10 + b0;
            const float rx = yv*m01 + xv*m11 + b1;
            const float fy = floorf(ry), fx = floorf(rx);
            const float wy1 = ry - fy, wx1 = rx - fx;
            const float wy0 = 1.0f - wy1, wx0 = 1.0f - wx1;
            const int iy = (int)fy - y0;
            const int ix = (int)fx - x0;
            const float* p0 = &buf[iy*BBW3 + ix*3];
            const float* p1 = p0 + BBW3;
            const float w00 = wy0*wx0, w01 = wy0*wx1;
            const float w10 = wy1*wx0, w11 = wy1*wx1;
            v[k*3+0] = w00*p0[0] + w01*p0[3] + w10*p1[0] + w11*p1[3];
            v[k*3+1] = w00*p0[1] + w01*p0[4] + w10*p1[1] + w11*p1[4];
            v[k*3+2] = w00*p0[2] + w01*p0[5] + w10*p1[2] + w11*p1[5];
        }
        float* ob = out + (i*IMG_W + j0 + col)*3;   // 48B chunk, 16B aligned
        *(float4*)(ob+0) = make_float4(v[0], v[1], v[2],  v[3]);
        *(float4*)(ob+4) = make_float4(v[4], v[5], v[6],  v[7]);
        *(float4*)(ob+8) = make_float4(v[8], v[9], v[10], v[11]);
    };

    // ---- Prologue: fill buf 0 for tile 0.
    int y0c, x0c, nrc, nvc; bool fc;
    bbox(j0base, y0c, x0c, nrc, nvc, fc);
    if (fc) dmafill(lds[0], y0c, x0c, nrc, nvc);
    else    slowfill(lds[0], y0c, x0c, nrc);
    __syncthreads();    // vmcnt(0) drain -> buf 0 valid

    int cur = 0;
    for (int t = 0; t < NT; ++t) {
        const int j0 = j0base + t*TILE;
        int y0n, x0n, nrn, nvn; bool fn = false;
        if (t+1 < NT) {
            bbox(j0 + TILE, y0n, x0n, nrn, nvn, fn);
            if (fn) dmafill(lds[cur^1], y0n, x0n, nrn, nvn); // DMA in flight
            else    slowfill(lds[cur^1], y0n, x0n, nrn);     // rare border
        }
        compute(lds[cur], j0, y0c, x0c);
        __syncthreads();  // drains prefetch DMA + syncs buffer swap
        y0c = y0n; x0c = x0n; cur ^= 1;
    }
}

extern "C" void kernel_launch(void* const* d_in, const int* in_sizes, int n_in,
                              void* d_out, int out_size, void* d_ws, size_t ws_size,
                              hipStream_t stream) {
    const float* img = (const float*)d_in[0];   // (2048,2048,3) f32
    const float* M   = (const float*)d_in[1];   // (3,3) f32 row-major
    float* out = (float*)d_out;                 // (2048,2048,3) f32

    dim3 grid((IMG_H / TILE) * (IMG_W / (TILE * NT))), block(256);
    hipLaunchKernelGGL(affine_dbuf_kernel, grid, block, 0, stream, img, M, out);
}

// Round 13
// 113.743 us; speedup vs baseline: 1.4039x; 1.0717x over previous
//
#include <hip/hip_runtime.h>

// RandomAffine: double-buffered LDS pipeline, occupancy-preserving tiles.
// Tile = 16x32 output px; staged bbox <= 31 rows x 47 px -> 32x(37 float4)
// = 18944 B per buffer, dbuf = 37888 B -> 4 blocks/CU x 4 waves = 16
// waves/CU, grid 1024 blocks fully resident. Per tile: issue next tile's
// global_load_lds DMA into buf^1 (in flight under compute), compute current
// from buf, one __syncthreads (vmcnt(0) drain completes prefetch). Compute
// keeps the stride-1-lane mapping (low bank conflicts, R11 lesson) and no
// register staging (R10 lesson: scratch spills).

#define IMG_H 2048
#define IMG_W 2048
#define TH    16           // tile height
#define TW    32           // tile width
#define NT    8            // j-tiles per block
#define BBH   32           // staged rows capacity (worst dynamic 31)
#define NV4C  37           // staged float4/row capacity (worst dynamic 36)
#define STR   (NV4C * 4)   // 148 floats per staged row (592 B, 16B-mult)
#define BUFN  (BBH * STR)  // 4736 floats = 18944 B per buffer

__device__ __forceinline__ int reflect2048(int i) {
    // scipy 'reflect' (duplicate-edge), period 2n, n=2048.
    int p = i & 4095;
    return (p < 2048) ? p : (4095 - p);
}

__device__ __forceinline__ void gl2lds16(const float* g, float* l) {
    // 16B per lane, LDS dest = wave-uniform base + lane*16 (HW rule).
    __builtin_amdgcn_global_load_lds(
        (const __attribute__((address_space(1))) void*)g,
        (__attribute__((address_space(3))) void*)l,
        16, 0, 0);
}

__global__ __launch_bounds__(256) void affine_dbuf16_kernel(
    const float* __restrict__ img, const float* __restrict__ Mp,
    float* __restrict__ out)
{
    __shared__ float lds[2][BUFN];       // 37888 B total

    const int tid = threadIdx.x;
    const int grp = blockIdx.x & 7;      // 8 groups of NT tiles along j
    const int tby = blockIdx.x >> 3;     // 128 tile-rows
    const int i0 = tby * TH;
    const int j0base = grp * (TW * NT);

    const float step = 2048.0f / 2047.0f;
    const float m00 = Mp[0], m01 = Mp[1];
    const float m10 = Mp[3], m11 = Mp[4];
    const float b0 = Mp[6] + 1024.0f, b1 = Mp[7] + 1024.0f;

    const float yv0 = fmaf((float)i0,          step, -1024.0f);
    const float yv1 = fmaf((float)(i0 + TH-1), step, -1024.0f);

    // Per-tile bbox from the 4 corners (affine -> extremes at corners).
    auto bbox = [&](int j0, int& y0, int& x0, int& nrows, int& nv4, bool& fast) {
        const float xva = fmaf((float)j0,        step, -1024.0f);
        const float xvb = fmaf((float)(j0+TW-1), step, -1024.0f);
        const float rya = yv0*m00 + xva*m10 + b0, ryb = yv0*m00 + xvb*m10 + b0;
        const float ryc = yv1*m00 + xva*m10 + b0, ryd = yv1*m00 + xvb*m10 + b0;
        const float rxa = yv0*m01 + xva*m11 + b1, rxb = yv0*m01 + xvb*m11 + b1;
        const float rxc = yv1*m01 + xva*m11 + b1, rxd = yv1*m01 + xvb*m11 + b1;
        const float miny = fminf(fminf(rya,ryb), fminf(ryc,ryd));
        const float maxy = fmaxf(fmaxf(rya,ryb), fmaxf(ryc,ryd));
        const float minx = fminf(fminf(rxa,rxb), fminf(rxc,rxd));
        const float maxx = fmaxf(fmaxf(rxa,rxb), fmaxf(rxc,rxd));
        y0 = (int)floorf(miny) - 1;
        nrows = (int)floorf(maxy) + 3 - y0;              // <= 31
        if (nrows > BBH) nrows = BBH;                    // capacity belt
        x0 = ((int)floorf(minx) - 1) & ~3;               // 16B align
        const int xw = (int)floorf(maxx) + 3 - x0;       // <= 47
        nv4 = (xw * 3 + 3) >> 2;                         // <= 36
        if (nv4 > NV4C) nv4 = NV4C;
        fast = (x0 >= 0) && (x0*3 + nv4*4 <= IMG_W*3);
    };

    auto dmafill = [&](float* buf, int y0, int x0, int nrows, int nv4) {
        const int wid = tid >> 6, lane = tid & 63;
        if (lane < nv4) {
            for (int r = wid; r < nrows; r += 4) {
                const int gy = reflect2048(y0 + r);
                gl2lds16(img + gy*(IMG_W*3) + x0*3 + lane*4, &buf[r*STR]);
            }
        }
    };
    auto slowfill = [&](float* buf, int y0, int x0, int nrows) {
        for (int e = tid; e < nrows*48; e += 256) {
            const int r  = e / 48;
            const int xx = e - r*48;
            const int gy = reflect2048(y0 + r);
            const int gx = reflect2048(x0 + xx);
            const float* s = img + (gy*IMG_W + gx)*3;
            float* d = &buf[r*STR + xx*3];
            d[0] = s[0]; d[1] = s[1]; d[2] = s[2];
        }
    };

    auto compute = [&](const float* buf, int j0, int y0, int x0) {
        #pragma unroll
        for (int pass = 0; pass < 2; ++pass) {
            const int row = pass*8 + (tid >> 5);   // 0..15
            const int col = tid & 31;              // stride-1 lanes
            const int i = i0 + row, j = j0 + col;
            const float yv = fmaf((float)i, step, -1024.0f);
            const float xv = fmaf((float)j, step, -1024.0f);
            const float ry = yv*m00 + xv*m10 + b0;
            const float rx = yv*m01 + xv*m11 + b1;
            const float fy = floorf(ry), fx = floorf(rx);
            const float wy1 = ry - fy, wx1 = rx - fx;
            const float wy0 = 1.0f - wy1, wx0 = 1.0f - wx1;
            const int iy = (int)fy - y0;
            const int ix = (int)fx - x0;
            const float* p0 = &buf[iy*STR + ix*3];
            const float* p1 = p0 + STR;
            const float w00 = wy0*wx0, w01 = wy0*wx1;
            const float w10 = wy1*wx0, w11 = wy1*wx1;
            float* ob = out + (i*IMG_W + j)*3;
            ob[0] = w00*p0[0] + w01*p0[3] + w10*p1[0] + w11*p1[3];
            ob[1] = w00*p0[1] + w01*p0[4] + w10*p1[1] + w11*p1[4];
            ob[2] = w00*p0[2] + w01*p0[5] + w10*p1[2] + w11*p1[5];
        }
    };

    // ---- Prologue: fill buf 0 for tile 0.
    int y0c, x0c, nrc, nvc; bool fc;
    bbox(j0base, y0c, x0c, nrc, nvc, fc);
    if (fc) dmafill(lds[0], y0c, x0c, nrc, nvc);
    else    slowfill(lds[0], y0c, x0c, nrc);
    __syncthreads();    // vmcnt(0) drain -> buf 0 valid

    int cur = 0;
    for (int t = 0; t < NT; ++t) {
        const int j0 = j0base + t*TW;
        int y0n, x0n, nrn, nvn; bool fn = false;
        if (t+1 < NT) {
            bbox(j0 + TW, y0n, x0n, nrn, nvn, fn);
            if (fn) dmafill(lds[cur^1], y0n, x0n, nrn, nvn); // DMA in flight
            else    slowfill(lds[cur^1], y0n, x0n, nrn);     // rare border
        }
        compute(lds[cur], j0, y0c, x0c);
        __syncthreads();  // drains prefetch DMA + syncs buffer swap
        y0c = y0n; x0c = x0n; cur ^= 1;
    }
}

extern "C" void kernel_launch(void* const* d_in, const int* in_sizes, int n_in,
                              void* d_out, int out_size, void* d_ws, size_t ws_size,
                              hipStream_t stream) {
    const float* img = (const float*)d_in[0];   // (2048,2048,3) f32
    const float* M   = (const float*)d_in[1];   // (3,3) f32 row-major
    float* out = (float*)d_out;                 // (2048,2048,3) f32

    dim3 grid((IMG_H / TH) * (IMG_W / (TW * NT))), block(256);
    hipLaunchKernelGGL(affine_dbuf16_kernel, grid, block, 0, stream, img, M, out);
}

// Round 16
// 103.821 us; speedup vs baseline: 1.5380x; 1.0956x over previous
//
#include <hip/hip_runtime.h>

// RandomAffine: single-buffer LDS staging, occupancy-maximized.
// R13 lesson: intra-block dbuf pipelining lost to its own overhead; the
// winning lever is cross-block TLP. Tile = 16x32 output px -> staged bbox
// <= 31 rows x 47 px, buffer 32 x 148 floats = 18944 B -> 8 blocks/CU
// x 4 waves = 32 waves/CU (100% occupancy). Simple per-tile flow (R9):
// global_load_lds DMA fill -> barrier -> bilinear compute from LDS.
// With ~8 resident blocks per CU, fills from some blocks always overlap
// compute of others, keeping the HBM pipe fed.

#define IMG_H 2048
#define IMG_W 2048
#define TH    16           // tile height
#define TW    32           // tile width
#define BBH   32           // staged rows capacity (worst dynamic 31)
#define NV4C  37           // staged float4/row capacity (worst dynamic 36)
#define STR   (NV4C * 4)   // 148 floats per staged row (592 B)
#define BUFN  (BBH * STR)  // 4736 floats = 18944 B

__device__ __forceinline__ int reflect2048(int i) {
    // scipy 'reflect' (duplicate-edge), period 2n, n=2048.
    int p = i & 4095;
    return (p < 2048) ? p : (4095 - p);
}

__device__ __forceinline__ void gl2lds16(const float* g, float* l) {
    // 16B per lane, LDS dest = wave-uniform base + lane*16 (HW rule).
    __builtin_amdgcn_global_load_lds(
        (const __attribute__((address_space(1))) void*)g,
        (__attribute__((address_space(3))) void*)l,
        16, 0, 0);
}

__global__ __launch_bounds__(256) void affine_occ_kernel(
    const float* __restrict__ img, const float* __restrict__ Mp,
    float* __restrict__ out)
{
    __shared__ float lds[BUFN];          // 18944 B -> 8 blocks/CU

    const int tid = threadIdx.x;
    const int tbx = blockIdx.x & 63;     // 64 tile-cols; bid%8 keeps
    const int tby = blockIdx.x >> 6;     // vertical neighbors on one XCD
    const int i0 = tby * TH, j0 = tbx * TW;

    const float step = 2048.0f / 2047.0f;
    const float m00 = Mp[0], m01 = Mp[1];
    const float m10 = Mp[3], m11 = Mp[4];
    const float b0 = Mp[6] + 1024.0f, b1 = Mp[7] + 1024.0f;

    const float yv0 = fmaf((float)i0,          step, -1024.0f);
    const float yv1 = fmaf((float)(i0 + TH-1), step, -1024.0f);
    const float xva = fmaf((float)j0,          step, -1024.0f);
    const float xvb = fmaf((float)(j0 + TW-1), step, -1024.0f);

    // Bbox of the tile's affine preimage (extremes at corners).
    const float rya = yv0*m00 + xva*m10 + b0, ryb = yv0*m00 + xvb*m10 + b0;
    const float ryc = yv1*m00 + xva*m10 + b0, ryd = yv1*m00 + xvb*m10 + b0;
    const float rxa = yv0*m01 + xva*m11 + b1, rxb = yv0*m01 + xvb*m11 + b1;
    const float rxc = yv1*m01 + xva*m11 + b1, rxd = yv1*m01 + xvb*m11 + b1;

    const float miny = fminf(fminf(rya,ryb), fminf(ryc,ryd));
    const float maxy = fmaxf(fmaxf(rya,ryb), fmaxf(ryc,ryd));
    const float minx = fminf(fminf(rxa,rxb), fminf(rxc,rxd));
    const float maxx = fmaxf(fmaxf(rxa,rxb), fmaxf(rxc,rxd));

    const int y0 = (int)floorf(miny) - 1;
    int nrows = (int)floorf(maxy) + 3 - y0;              // <= 31
    if (nrows > BBH) nrows = BBH;
    const int x0 = ((int)floorf(minx) - 1) & ~3;         // 16B align
    const int xw = (int)floorf(maxx) + 3 - x0;           // <= 47
    int nv4 = (xw * 3 + 3) >> 2;                         // <= 36
    if (nv4 > NV4C) nv4 = NV4C;

    // ---- Stage bbox into LDS.
    if (x0 >= 0 && x0*3 + nv4*4 <= IMG_W*3) {
        const int wid = tid >> 6, lane = tid & 63;
        if (lane < nv4) {
            for (int r = wid; r < nrows; r += 4) {
                const int gy = reflect2048(y0 + r);
                gl2lds16(img + gy*(IMG_W*3) + x0*3 + lane*4, &lds[r*STR]);
            }
        }
    } else {
        // Border tiles: per-element x reflect.
        for (int e = tid; e < nrows*48; e += 256) {
            const int r  = e / 48;
            const int xx = e - r*48;
            const int gy = reflect2048(y0 + r);
            const int gx = reflect2048(x0 + xx);
            const float* s = img + (gy*IMG_W + gx)*3;
            float* d = &lds[r*STR + xx*3];
            d[0] = s[0]; d[1] = s[1]; d[2] = s[2];
        }
    }
    __syncthreads();   // vmcnt(0) drain -> LDS valid

    // ---- 2 passes: 8 rows x 32 stride-1 cols per pass.
    #pragma unroll
    for (int pass = 0; pass < 2; ++pass) {
        const int row = pass*8 + (tid >> 5);   // 0..15
        const int col = tid & 31;
        const int i = i0 + row, j = j0 + col;
        const float yv = fmaf((float)i, step, -1024.0f);
        const float xv = fmaf((float)j, step, -1024.0f);
        const float ry = yv*m00 + xv*m10 + b0;
        const float rx = yv*m01 + xv*m11 + b1;
        const float fy = floorf(ry), fx = floorf(rx);
        const float wy1 = ry - fy, wx1 = rx - fx;
        const float wy0 = 1.0f - wy1, wx0 = 1.0f - wx1;
        const int iy = (int)fy - y0;
        const int ix = (int)fx - x0;
        const float* p0 = &lds[iy*STR + ix*3];
        const float* p1 = p0 + STR;
        const float w00 = wy0*wx0, w01 = wy0*wx1;
        const float w10 = wy1*wx0, w11 = wy1*wx1;
        float* ob = out + (i*IMG_W + j)*3;
        ob[0] = w00*p0[0] + w01*p0[3] + w10*p1[0] + w11*p1[3];
        ob[1] = w00*p0[1] + w01*p0[4] + w10*p1[1] + w11*p1[4];
        ob[2] = w00*p0[2] + w01*p0[5] + w10*p1[2] + w11*p1[5];
    }
}

extern "C" void kernel_launch(void* const* d_in, const int* in_sizes, int n_in,
                              void* d_out, int out_size, void* d_ws, size_t ws_size,
                              hipStream_t stream) {
    const float* img = (const float*)d_in[0];   // (2048,2048,3) f32
    const float* M   = (const float*)d_in[1];   // (3,3) f32 row-major
    float* out = (float*)d_out;                 // (2048,2048,3) f32

    dim3 grid((IMG_H / TH) * (IMG_W / TW)), block(256);  // 8192 blocks
    hipLaunchKernelGGL(affine_occ_kernel, grid, block, 0, stream, img, M, out);
}